// Round 2
// baseline (444.358 us; speedup 1.0000x reference)
//
#include <hip/hip_runtime.h>

#define NN 50000
#define NE 400000
#define SCAN_NB 196   // ceil(50000/256)

__global__ void k_hist(const int* __restrict__ rcv, int* __restrict__ cnt){
  int e = blockIdx.x*256 + threadIdx.x;
  if (e < NE) atomicAdd(&cnt[rcv[e]], 1);
}

__global__ void k_scanA(const int* __restrict__ cnt, int* __restrict__ bsum){
  __shared__ int sh[256];
  int i = blockIdx.x*256 + threadIdx.x;
  int v = (i < NN) ? cnt[i] : 0;
  sh[threadIdx.x] = v; __syncthreads();
  for (int off=128; off>0; off>>=1){
    if (threadIdx.x < off) sh[threadIdx.x] += sh[threadIdx.x+off];
    __syncthreads();
  }
  if (threadIdx.x==0) bsum[blockIdx.x] = sh[0];
}

__global__ void k_scanB(int* __restrict__ bsum){
  __shared__ int sh[256];
  int t = threadIdx.x;
  int v = (t < SCAN_NB) ? bsum[t] : 0;
  sh[t] = v; __syncthreads();
  for (int off=1; off<256; off<<=1){
    int x = (t>=off)? sh[t-off] : 0;
    __syncthreads();
    sh[t] += x;
    __syncthreads();
  }
  if (t < SCAN_NB) bsum[t] = sh[t] - v;   // exclusive
}

__global__ void k_scanC(const int* __restrict__ cnt, const int* __restrict__ bsum,
                        int* __restrict__ offs, int* __restrict__ cursor){
  __shared__ int sh[256];
  int t = threadIdx.x;
  int i = blockIdx.x*256 + t;
  int v = (i < NN) ? cnt[i] : 0;
  sh[t] = v; __syncthreads();
  for (int off=1; off<256; off<<=1){
    int x = (t>=off)? sh[t-off] : 0;
    __syncthreads();
    sh[t] += x;
    __syncthreads();
  }
  int excl = sh[t] - v + bsum[blockIdx.x];
  if (i < NN){ offs[i] = excl; cursor[i] = excl; }
}

__global__ void k_scatter(const int* __restrict__ rcv, const int* __restrict__ snd,
                          int* __restrict__ cursor, int* __restrict__ csr_snd){
  int e = blockIdx.x*256 + threadIdx.x;
  if (e < NE){
    int p = atomicAdd(&cursor[rcv[e]], 1);
    csr_snd[p] = snd[e];
  }
}

// Fused kernel: per node, aggregate A[m][k] = sum_e feat[snd][m]*sh_k(e) in
// registers (lane l: m=l&31, k-half=l>>5), then transform with W (LDS-staged)
// to produce the output row. Eliminates Ge/Gsc entirely: per-edge gather is
// 128B of feat (L2-hot, feat=6.4MB) instead of 1KB of Ge (L3, 51.2MB).
// 16 waves/block = 16 nodes/block; sh staging buffer (2KB/wave) is reused as
// the A transpose buffer in the epilogue.
__global__ __launch_bounds__(1024) void k_edge(
    const float* __restrict__ pos, const float* __restrict__ feat,
    const float* __restrict__ W0, const float* __restrict__ W1,
    const float* __restrict__ W2, const float* __restrict__ W3,
    const float* __restrict__ Wsc,
    const int* __restrict__ offs, const int* __restrict__ cnt,
    const int* __restrict__ csr_snd, float* __restrict__ out)
{
  __shared__ float Wl[5][2048];                 // 40 KB
  __shared__ __align__(16) float sm[16][512];   // 32 KB: sh staging, then A
  __shared__ int slist[16][32];                 // 2 KB

  const int tid = threadIdx.x;
  {
    const float* src[5] = {W0,W1,W2,W3,Wsc};
    #pragma unroll
    for (int w=0; w<5; ++w)
      for (int i=tid; i<2048; i+=1024)
        Wl[w][i] = src[w][i];
  }
  __syncthreads();

  const int wv = tid>>6, lane = tid&63;
  const int ml = lane&31, hh = lane>>5;         // m index, k-half
  const int n = blockIdx.x*16 + wv;             // 3125*16 == 50000
  const float pnx=pos[n*3], pny=pos[n*3+1], pnz=pos[n*3+2];
  const int start = offs[n], deg = cnt[n];
  const int nch = (deg+31)>>5;

  float acc[8];
  #pragma unroll
  for (int j=0;j<8;++j) acc[j]=0.f;

  const float SC3=1.7320508f, SC5=2.236068f, SC7=2.6457513f, SC15=3.8729833f,
              SC42=6.4807407f, SC70=8.3666003f, SC105=10.246951f;

  for (int c=0; c<nch; ++c){
    const int base = c<<5;
    int cn = deg - base; cn = (cn>32)?32:cn;    // >=1 inside loop
    if (lane < cn){
      int s = csr_snd[start+base+lane];
      float rx = pnx - pos[s*3];
      float ry = pny - pos[s*3+1];
      float rz = pnz - pos[s*3+2];
      float r = sqrtf(rx*rx+ry*ry+rz*rz);
      float inv = 1.0f/fmaxf(r,1e-12f);
      float x=rx*inv, y=ry*inv, z=rz*inv;
      float x2=x*x, y2=y*y, z2=z*z;
      float s1=SC3*x, s2=SC3*y, s3=SC3*z;
      float s4=SC15*x*y, s5=SC15*y*z, s6=0.5f*SC5*(3.f*z2-1.f), s7=SC15*x*z;
      float s8=0.5f*SC15*(x2-y2);
      float s9 =0.25f*SC70*y*(3.f*x2-y2);
      float s10=SC105*x*y*z;
      float s11=0.25f*SC42*y*(5.f*z2-1.f);
      float s12=0.5f*SC7*z*(5.f*z2-3.f);
      float s13=0.25f*SC42*x*(5.f*z2-1.f);
      float s14=0.5f*SC105*z*(x2-y2);
      float s15=0.25f*SC70*x*(x2-3.f*y2);
      float4* wp = (float4*)&sm[wv][lane*16];
      wp[0] = make_float4(1.0f,s1,s2,s3);
      wp[1] = make_float4(s4,s5,s6,s7);
      wp[2] = make_float4(s8,s9,s10,s11);
      wp[3] = make_float4(s12,s13,s14,s15);
      slist[wv][lane] = s;
    }
    // same-wave LDS producer->consumer ordering (waves are independent)
    asm volatile("s_waitcnt lgkmcnt(0)" ::: "memory");
    #pragma unroll 4
    for (int it=0; it<cn; ++it){
      int s = __builtin_amdgcn_readfirstlane(slist[wv][it]);
      float f = feat[(size_t)s*32 + ml];        // 128B segment, L2-hot
      const float4* rp = (const float4*)&sm[wv][it*16 + hh*8];
      float4 q0=rp[0], q1=rp[1];
      acc[0]+=f*q0.x; acc[1]+=f*q0.y; acc[2]+=f*q0.z; acc[3]+=f*q0.w;
      acc[4]+=f*q1.x; acc[5]+=f*q1.y; acc[6]+=f*q1.z; acc[7]+=f*q1.w;
    }
    asm volatile("" ::: "memory");  // reads before next chunk's overwrites
  }

  // ---- epilogue: A (regs) -> LDS transpose -> per-node transform ----
  {
    float4* ap = (float4*)&sm[wv][ml*16 + hh*8];   // A[m][k] at sm[wv][m*16+k]
    ap[0] = make_float4(acc[0],acc[1],acc[2],acc[3]);
    ap[1] = make_float4(acc[4],acc[5],acc[6],acc[7]);
  }
  asm volatile("s_waitcnt lgkmcnt(0)" ::: "memory");

  float oa[16];
  #pragma unroll
  for (int k=0;k<16;++k) oa[k]=0.f;
  float osc = 0.f;
  const float4* fs4 = (const float4*)(feat + (size_t)n*32);

  #pragma unroll 2
  for (int g=0; g<8; ++g){
    float4 fsv = fs4[g];                           // uniform addr, L1-hot
    #pragma unroll
    for (int mm=0; mm<4; ++mm){
      const int m = g*4+mm;
      const float fsm = (mm==0)?fsv.x:(mm==1)?fsv.y:(mm==2)?fsv.z:fsv.w;
      const float4* Ap = (const float4*)&sm[wv][m*16];  // broadcast reads
      float4 a0=Ap[0], a1=Ap[1], a2=Ap[2], a3=Ap[3];
      float w0=Wl[0][m*64+lane], w1=Wl[1][m*64+lane], w2=Wl[2][m*64+lane],
            w3=Wl[3][m*64+lane], w4=Wl[4][m*64+lane];
      oa[0] += a0.x*w0;
      oa[1] += a0.y*w1; oa[2] += a0.z*w1; oa[3] += a0.w*w1;
      oa[4] += a1.x*w2; oa[5] += a1.y*w2; oa[6] += a1.z*w2;
      oa[7] += a1.w*w2; oa[8] += a2.x*w2;
      oa[9] += a2.y*w3; oa[10]+= a2.z*w3; oa[11]+= a2.w*w3;
      oa[12]+= a3.x*w3; oa[13]+= a3.y*w3; oa[14]+= a3.z*w3; oa[15]+= a3.w*w3;
      osc += fsm*w4;
    }
  }

  const float S = 0.17677669529663687f;   // 1/sqrt(32)
  const float S8 = S*0.125f;              // edge terms also carry /DENOM
  float* o = out + (size_t)n*1024;
  o[lane] = oa[0]*S8 + osc*S;
  #pragma unroll
  for (int i=0;i<3;++i) o[64  + lane*3 + i] = oa[1+i]*S8;
  #pragma unroll
  for (int i=0;i<5;++i) o[256 + lane*5 + i] = oa[4+i]*S8;
  #pragma unroll
  for (int i=0;i<7;++i) o[576 + lane*7 + i] = oa[9+i]*S8;
}

extern "C" void kernel_launch(void* const* d_in, const int* in_sizes, int n_in,
                              void* d_out, int out_size, void* d_ws, size_t ws_size,
                              hipStream_t stream) {
  const float* pos  = (const float*)d_in[0];
  const float* feat = (const float*)d_in[1];
  const float* W0   = (const float*)d_in[2];
  const float* W1   = (const float*)d_in[3];
  const float* W2   = (const float*)d_in[4];
  const float* W3   = (const float*)d_in[5];
  const float* Wsc  = (const float*)d_in[6];
  const int*  snd   = (const int*)d_in[7];
  const int*  rcv   = (const int*)d_in[8];
  float* out = (float*)d_out;

  int* ws      = (int*)d_ws;
  int* cnt     = ws;            // 50000
  int* offs    = ws + 50000;    // 50000
  int* cursor  = ws + 100000;   // 50000
  int* bsum    = ws + 150000;   // 256
  int* csr_snd = ws + 150272;   // 400000 (total ~2.2 MB of workspace)

  hipMemsetAsync(cnt, 0, NN*sizeof(int), stream);
  k_hist   <<<(NE+255)/256, 256, 0, stream>>>(rcv, cnt);
  k_scanA  <<<SCAN_NB, 256, 0, stream>>>(cnt, bsum);
  k_scanB  <<<1, 256, 0, stream>>>(bsum);
  k_scanC  <<<SCAN_NB, 256, 0, stream>>>(cnt, bsum, offs, cursor);
  k_scatter<<<(NE+255)/256, 256, 0, stream>>>(rcv, snd, cursor, csr_snd);
  k_edge   <<<3125, 1024, 0, stream>>>(pos, feat, W0, W1, W2, W3, Wsc,
                                       offs, cnt, csr_snd, out);
}